// Round 6
// baseline (467.673 us; speedup 1.0000x reference)
//
#include <hip/hip_runtime.h>
#include <cstdint>
#include <cstddef>

#define BB 2
#define QQ 2048
#define KK_ 2048
#define HH 16
#define DD 64
#define DVV 64
#define NEG_INF_F (-1e9f)

static constexpr size_t CTX_ELEMS = (size_t)BB * QQ * HH * DVV;  // 4,194,304

typedef _Float16 f16x8 __attribute__((ext_vector_type(8)));
typedef _Float16 f16x4 __attribute__((ext_vector_type(4)));
typedef _Float16 f16x2 __attribute__((ext_vector_type(2)));
typedef float    f32x4 __attribute__((ext_vector_type(4)));

// workspace layout (float offsets)
#define RQ_OFF    0        // [B][H][Q]  0.125*||q_row||
#define KPART_OFF 65536    // [B*H][8]   partial max ||k_row|| per chunk
#define M_OFF     65792    // [B][H][Q]  upper bound M per row

// ---------------------------------------------------------------------------
// Prep A: per (b,h,chunk): rq rows + partial kmax (over valid k only).
// ---------------------------------------------------------------------------
__global__ __launch_bounds__(256)
void prep_norms(const float* __restrict__ qs, const float* __restrict__ ks,
                const int* __restrict__ vlen, float* __restrict__ ws) {
  float* rq    = ws + RQ_OFF;
  float* kpart = ws + KPART_OFF;
  const int id = blockIdx.x;            // 0..255
  const int bh = id & 31, c = id >> 5;  // chunk 0..7
  const int h = bh & 15, b = bh >> 4;
  const int vl = vlen[b];
  const int t = threadIdx.x;
  const int grp = t >> 4, l16 = t & 15;
  const int w = t >> 6, l = t & 63;
  __shared__ float red[4];
  float km2 = 0.f;                      // max squared norm
  const int base = c * 256;
  for (int i = 0; i < 16; ++i) {
    const int r = base + i * 16 + grp;
    {
      const float4 v = *(const float4*)(qs + ((size_t)(b * QQ + r) * HH + h) * DD + l16 * 4);
      float s = v.x * v.x + v.y * v.y + v.z * v.z + v.w * v.w;
      s += __shfl_xor(s, 1); s += __shfl_xor(s, 2);
      s += __shfl_xor(s, 4); s += __shfl_xor(s, 8);
      if (l16 == 0) rq[(size_t)(b * HH + h) * QQ + r] = sqrtf(s) * 0.125f;
    }
    if (r < vl) {
      const float4 v = *(const float4*)(ks + ((size_t)(b * KK_ + r) * HH + h) * DD + l16 * 4);
      float s = v.x * v.x + v.y * v.y + v.z * v.z + v.w * v.w;
      s += __shfl_xor(s, 1); s += __shfl_xor(s, 2);
      s += __shfl_xor(s, 4); s += __shfl_xor(s, 8);
      km2 = fmaxf(km2, s);
    }
  }
  km2 = fmaxf(km2, __shfl_xor(km2, 16));
  km2 = fmaxf(km2, __shfl_xor(km2, 32));
  if (l == 0) red[w] = km2;
  __syncthreads();
  if (t == 0)
    kpart[bh * 8 + c] = sqrtf(fmaxf(fmaxf(red[0], red[1]), fmaxf(red[2], red[3])));
}

// ---------------------------------------------------------------------------
// Prep B: per (b,q): Brow = max_{k<vl} bias[q,k]; M[b,h,q] = rq*kmax + Brow.
// ---------------------------------------------------------------------------
__global__ __launch_bounds__(256)
void prep_m(const float* __restrict__ bias, const int* __restrict__ vlen,
            float* __restrict__ ws) {
  const float* rq    = ws + RQ_OFF;
  const float* kpart = ws + KPART_OFF;
  float* M = ws + M_OFF;
  const int id = blockIdx.x;            // 0..1023
  const int b = id >> 9;
  const int qb = (id & 511) * 4;
  const int t = threadIdx.x, w = t >> 6, l = t & 63;
  const int q = qb + w;
  const int vl = vlen[b];
  float m = -3e38f;
  for (int k0 = l * 4; k0 < vl; k0 += 256) {
    const float4 v = *(const float4*)(bias + (size_t)q * KK_ + k0);
    m = fmaxf(m, (k0 + 0 < vl) ? v.x : -3e38f);
    m = fmaxf(m, (k0 + 1 < vl) ? v.y : -3e38f);
    m = fmaxf(m, (k0 + 2 < vl) ? v.z : -3e38f);
    m = fmaxf(m, (k0 + 3 < vl) ? v.w : -3e38f);
  }
#pragma unroll
  for (int off = 1; off < 64; off <<= 1) m = fmaxf(m, __shfl_xor(m, off));
  if (l < 16) {
    const int h = l;
    float kmx = 0.f;
#pragma unroll
    for (int cc = 0; cc < 8; ++cc) kmx = fmaxf(kmx, kpart[(b * HH + h) * 8 + cc]);
    M[(size_t)(b * HH + h) * QQ + q] = rq[(size_t)(b * HH + h) * QQ + q] * kmx + m;
  }
}

// ---------------------------------------------------------------------------
// Main fused kernel. wg = (b,h, 64 q-rows), 256 thr (4 waves, 16 q each).
// Transposed-S MFMA: S^T = K*Q^T; each lane owns 4 CONTIGUOUS k per frag.
// K fragments loaded DIRECTLY from global (L1/L2-hot) -> pass 1 barrier-free.
// Pass 2: V^T double-buffered in LDS -> ONE barrier per tile. Fixed per-row
// upper bound M (prep kernels) removes all per-tile reductions.
// ---------------------------------------------------------------------------
__global__ __launch_bounds__(256, 5)
void fused_attn(const float* __restrict__ qs, const float* __restrict__ ks,
                const float* __restrict__ vs, const float* __restrict__ bias,
                const int* __restrict__ vlen, const float* __restrict__ ws,
                float* __restrict__ dout) {
  float* ctx  = dout;
  float* attn = dout + CTX_ELEMS;
  const float* Mbuf = ws + M_OFF;

  // XCD swizzle: XCD x owns q-tiles {4x..4x+3} x all 32 bh (bias L2-resident)
  const int x   = blockIdx.x;           // 0..1023
  const int xcd = x & 7;
  const int idx = x >> 3;               // 0..127, bh fastest
  const int qt  = xcd * 4 + (idx >> 5); // 0..31
  const int bh  = idx & 31;
  const int h   = bh & 15, b = bh >> 4;
  const int vl  = vlen[b];
  const int ntv = (vl + 63) >> 6;

  const int t = threadIdx.x;
  const int w = t >> 6, l = t & 63, fr = l & 15, g = l >> 4;
  const int q0 = qt * 64, qw = q0 + w * 16;
  const int myq = qw + fr;

  __shared__ _Float16 Vt[2][64][72];  // V^T tile [dv][k], double-buffered
  __shared__ _Float16 Pt[64][72];     // P tile [q][k] (same-wave only)

  // ---- zero-fill fully-masked attn tail ----
  {
    const int row = t >> 2;
    const int c0  = (t & 3) << 4;
    float* ap = attn + ((size_t)(b * HH + h) * QQ + q0 + row) * KK_ + c0;
    const f32x4 z = {0.f, 0.f, 0.f, 0.f};
    for (int k0 = ntv * 64; k0 < KK_; k0 += 64) {
      *(f32x4*)(ap + k0)      = z;
      *(f32x4*)(ap + k0 + 4)  = z;
      *(f32x4*)(ap + k0 + 8)  = z;
      *(f32x4*)(ap + k0 + 12) = z;
    }
  }

  // ---- Q B-fragments in registers, pre-scaled by 1/8 ----
  f16x8 bq[2];
  {
    const float* qp = qs + ((size_t)(b * QQ + myq) * HH + h) * DD + g * 8;
#pragma unroll
    for (int kk = 0; kk < 2; ++kk) {
      const float4 f0 = *(const float4*)(qp + kk * 32);
      const float4 f1 = *(const float4*)(qp + kk * 32 + 4);
      f16x8 v;
      v[0] = (_Float16)(f0.x * 0.125f); v[1] = (_Float16)(f0.y * 0.125f);
      v[2] = (_Float16)(f0.z * 0.125f); v[3] = (_Float16)(f0.w * 0.125f);
      v[4] = (_Float16)(f1.x * 0.125f); v[5] = (_Float16)(f1.y * 0.125f);
      v[6] = (_Float16)(f1.z * 0.125f); v[7] = (_Float16)(f1.w * 0.125f);
      bq[kk] = v;
    }
  }

  const float Mq = Mbuf[(size_t)(b * HH + h) * QQ + myq];
  const float* biasq = bias + (size_t)myq * KK_;
  float* attnq = attn + ((size_t)(b * HH + h) * QQ + myq) * KK_;

  const int rho = t & 31, dlt = t >> 5;          // V staging (pairs)

#define KADDR(k) (ks + ((size_t)(b * KK_ + (k)) * HH + h) * DD)
#define VADDR(k) (vs + ((size_t)(b * KK_ + (k)) * HH + h) * DVV)

  // Direct K fragment load: row k0+c*16+fr, d = kk*32+g*8..+8 (32B contig).
#define LOAD_KFRAG(ka, k0arg, c)                                    \
  {                                                                 \
    const float* kp = KADDR((k0arg) + (c) * 16 + fr) + g * 8;       \
    _Pragma("unroll") for (int kk = 0; kk < 2; ++kk) {              \
      const float4 u0 = *(const float4*)(kp + kk * 32);             \
      const float4 u1 = *(const float4*)(kp + kk * 32 + 4);         \
      f16x8 kv;                                                     \
      kv[0] = (_Float16)u0.x; kv[1] = (_Float16)u0.y;               \
      kv[2] = (_Float16)u0.z; kv[3] = (_Float16)u0.w;               \
      kv[4] = (_Float16)u1.x; kv[5] = (_Float16)u1.y;               \
      kv[6] = (_Float16)u1.z; kv[7] = (_Float16)u1.w;               \
      ka[kk] = kv;                                                  \
    }                                                               \
  }

  // ================= PASS 1: lsum with fixed M (no barriers) =================
  float lsum = 0.f;
  for (int it = 0; it < ntv; ++it) {
    const int k0 = it * 64;
#pragma unroll
    for (int c = 0; c < 4; ++c) {
      f16x8 ka[2];
      LOAD_KFRAG(ka, k0, c);
      const float4 bz = *(const float4*)(biasq + k0 + c * 16 + g * 4);
      f32x4 acc = {0.f, 0.f, 0.f, 0.f};
      acc = __builtin_amdgcn_mfma_f32_16x16x32_f16(ka[0], bq[0], acc, 0, 0, 0);
      acc = __builtin_amdgcn_mfma_f32_16x16x32_f16(ka[1], bq[1], acc, 0, 0, 0);
      const int kb = k0 + c * 16 + g * 4;
      const float e0 = __expf(acc[0] + bz.x - Mq);
      const float e1 = __expf(acc[1] + bz.y - Mq);
      const float e2 = __expf(acc[2] + bz.z - Mq);
      const float e3 = __expf(acc[3] + bz.w - Mq);
      lsum += (kb + 0 < vl) ? e0 : 0.f;
      lsum += (kb + 1 < vl) ? e1 : 0.f;
      lsum += (kb + 2 < vl) ? e2 : 0.f;
      lsum += (kb + 3 < vl) ? e3 : 0.f;
    }
  }
  lsum += __shfl_xor(lsum, 16);
  lsum += __shfl_xor(lsum, 32);
  const float il = 1.f / lsum;

  // ================= PASS 2: attn write + PV (1 barrier/tile) ================
  f32x4 accv[4];
#pragma unroll
  for (int n = 0; n < 4; ++n) accv[n] = (f32x4){0.f, 0.f, 0.f, 0.f};

  float4 vr[4];

#define LOAD_V(k0arg)                                      \
  {                                                        \
    const float* vp0 = VADDR((k0arg) + 2 * rho) + dlt * 8; \
    vr[0] = ((const float4*)vp0)[0];                       \
    vr[1] = ((const float4*)vp0)[1];                       \
    const float* vp1 = VADDR((k0arg) + 2 * rho + 1) + dlt * 8; \
    vr[2] = ((const float4*)vp1)[0];                       \
    vr[3] = ((const float4*)vp1)[1];                       \
  }

#define STORE_V(buf)                                       \
  {                                                        \
    const float a0[8] = {vr[0].x, vr[0].y, vr[0].z, vr[0].w,\
                         vr[1].x, vr[1].y, vr[1].z, vr[1].w};\
    const float a1[8] = {vr[2].x, vr[2].y, vr[2].z, vr[2].w,\
                         vr[3].x, vr[3].y, vr[3].z, vr[3].w};\
    _Pragma("unroll") for (int i = 0; i < 8; ++i) {        \
      f16x2 pk; pk[0] = (_Float16)a0[i]; pk[1] = (_Float16)a1[i];\
      *(f16x2*)&Vt[buf][dlt * 8 + i][2 * rho] = pk;        \
    }                                                      \
  }

  LOAD_V(0);
  STORE_V(0);
  __syncthreads();

  int cur = 0;
  for (int it = 0; it < ntv; ++it) {
    const int k0 = it * 64;
    const bool pre = (it + 1 < ntv);
    if (pre) LOAD_V(k0 + 64);          // regs; lands under QK^T compute
#pragma unroll
    for (int c = 0; c < 4; ++c) {
      f16x8 ka[2];
      LOAD_KFRAG(ka, k0, c);
      const float4 bz = *(const float4*)(biasq + k0 + c * 16 + g * 4);
      f32x4 acc = {0.f, 0.f, 0.f, 0.f};
      acc = __builtin_amdgcn_mfma_f32_16x16x32_f16(ka[0], bq[0], acc, 0, 0, 0);
      acc = __builtin_amdgcn_mfma_f32_16x16x32_f16(ka[1], bq[1], acc, 0, 0, 0);
      const int kb = k0 + c * 16 + g * 4;
      const float e0 = __expf(acc[0] + bz.x - Mq) * il;
      const float e1 = __expf(acc[1] + bz.y - Mq) * il;
      const float e2 = __expf(acc[2] + bz.z - Mq) * il;
      const float e3 = __expf(acc[3] + bz.w - Mq) * il;
      f32x4 pv;
      pv[0] = (kb + 0 < vl) ? e0 : 0.f;
      pv[1] = (kb + 1 < vl) ? e1 : 0.f;
      pv[2] = (kb + 2 < vl) ? e2 : 0.f;
      pv[3] = (kb + 3 < vl) ? e3 : 0.f;
      *(f32x4*)(attnq + kb) = pv;      // regular store: L2 merges lines
      f16x4 ph;
      ph[0] = (_Float16)pv[0]; ph[1] = (_Float16)pv[1];
      ph[2] = (_Float16)pv[2]; ph[3] = (_Float16)pv[3];
      *(f16x4*)&Pt[w * 16 + fr][c * 16 + g * 4] = ph;
    }
    if (pre) STORE_V(cur ^ 1);         // other buffer; safe pre-barrier
    // same-wave LDS RAW on Pt: drain DS queue, then pin (rule #18)
    asm volatile("s_waitcnt lgkmcnt(0)" ::: "memory");
    __builtin_amdgcn_sched_barrier(0);
#pragma unroll
    for (int kk = 0; kk < 2; ++kk) {
      const f16x8 av = *(const f16x8*)&Pt[w * 16 + fr][kk * 32 + g * 8];
#pragma unroll
      for (int n = 0; n < 4; ++n) {
        const f16x8 bv = *(const f16x8*)&Vt[cur][n * 16 + fr][kk * 32 + g * 8];
        accv[n] = __builtin_amdgcn_mfma_f32_16x16x32_f16(av, bv, accv[n], 0, 0, 0);
      }
    }
    __syncthreads();                    // ONE barrier per tile
    cur ^= 1;
  }

  // ---- ctx store: col = dv = n*16+fr, row = q = qw + g*4 + r ----
#pragma unroll
  for (int n = 0; n < 4; ++n) {
#pragma unroll
    for (int r = 0; r < 4; ++r) {
      const size_t o = ((size_t)(b * QQ + qw + g * 4 + r) * HH + h) * DVV + n * 16 + fr;
      ctx[o] = accv[n][r];
    }
  }
#undef KADDR
#undef VADDR
#undef LOAD_KFRAG
#undef LOAD_V
#undef STORE_V
}

// ---------------------------------------------------------------------------
extern "C" void kernel_launch(void* const* d_in, const int* in_sizes, int n_in,
                              void* d_out, int out_size, void* d_ws, size_t ws_size,
                              hipStream_t stream) {
  (void)in_sizes; (void)n_in; (void)ws_size; (void)out_size;
  const float* qs   = (const float*)d_in[0];
  const float* ks   = (const float*)d_in[1];
  const float* vs   = (const float*)d_in[2];
  const float* bias = (const float*)d_in[3];
  const int*   vlen = (const int*)d_in[4];
  float* out = (float*)d_out;
  float* ws  = (float*)d_ws;

  prep_norms<<<dim3(256), dim3(256), 0, stream>>>(qs, ks, vlen, ws);
  prep_m<<<dim3(1024), dim3(256), 0, stream>>>(bias, vlen, ws);
  fused_attn<<<dim3(1024), dim3(256), 0, stream>>>(qs, ks, vs, bias, vlen, ws, out);
}

// Round 7
// 290.114 us; speedup vs baseline: 1.6120x; 1.6120x over previous
//
#include <hip/hip_runtime.h>
#include <cstdint>
#include <cstddef>

#define BB 2
#define QQ 2048
#define KK_ 2048
#define HH 16
#define DD 64
#define DVV 64
#define NEG_INF_F (-1e9f)

static constexpr size_t CTX_ELEMS = (size_t)BB * QQ * HH * DVV;  // 4,194,304

typedef _Float16 f16x8 __attribute__((ext_vector_type(8)));
typedef _Float16 f16x4 __attribute__((ext_vector_type(4)));
typedef _Float16 f16x2 __attribute__((ext_vector_type(2)));
typedef float    f32x4 __attribute__((ext_vector_type(4)));

// workspace layout (float offsets)
#define RQ_OFF    0        // [B][H][Q]  0.125*||q_row||
#define KPART_OFF 65536    // [B*H][8]   partial max ||k_row|| per chunk
#define M_OFF     65792    // [B][H][Q]  upper bound M per row

// ---------------------------------------------------------------------------
// Prep A: per (b,h,chunk): rq rows + partial kmax (over valid k only).
// ---------------------------------------------------------------------------
__global__ __launch_bounds__(256)
void prep_norms(const float* __restrict__ qs, const float* __restrict__ ks,
                const int* __restrict__ vlen, float* __restrict__ ws) {
  float* rq    = ws + RQ_OFF;
  float* kpart = ws + KPART_OFF;
  const int id = blockIdx.x;            // 0..255
  const int bh = id & 31, c = id >> 5;  // chunk 0..7
  const int h = bh & 15, b = bh >> 4;
  const int vl = vlen[b];
  const int t = threadIdx.x;
  const int grp = t >> 4, l16 = t & 15;
  const int w = t >> 6, l = t & 63;
  __shared__ float red[4];
  float km2 = 0.f;                      // max squared norm
  const int base = c * 256;
  for (int i = 0; i < 16; ++i) {
    const int r = base + i * 16 + grp;
    {
      const float4 v = *(const float4*)(qs + ((size_t)(b * QQ + r) * HH + h) * DD + l16 * 4);
      float s = v.x * v.x + v.y * v.y + v.z * v.z + v.w * v.w;
      s += __shfl_xor(s, 1); s += __shfl_xor(s, 2);
      s += __shfl_xor(s, 4); s += __shfl_xor(s, 8);
      if (l16 == 0) rq[(size_t)(b * HH + h) * QQ + r] = sqrtf(s) * 0.125f;
    }
    if (r < vl) {
      const float4 v = *(const float4*)(ks + ((size_t)(b * KK_ + r) * HH + h) * DD + l16 * 4);
      float s = v.x * v.x + v.y * v.y + v.z * v.z + v.w * v.w;
      s += __shfl_xor(s, 1); s += __shfl_xor(s, 2);
      s += __shfl_xor(s, 4); s += __shfl_xor(s, 8);
      km2 = fmaxf(km2, s);
    }
  }
  km2 = fmaxf(km2, __shfl_xor(km2, 16));
  km2 = fmaxf(km2, __shfl_xor(km2, 32));
  if (l == 0) red[w] = km2;
  __syncthreads();
  if (t == 0)
    kpart[bh * 8 + c] = sqrtf(fmaxf(fmaxf(red[0], red[1]), fmaxf(red[2], red[3])));
}

// ---------------------------------------------------------------------------
// Prep B: per (b,q): Brow = max_{k<vl} bias[q,k]; M[b,h,q] = rq*kmax + Brow.
// ---------------------------------------------------------------------------
__global__ __launch_bounds__(256)
void prep_m(const float* __restrict__ bias, const int* __restrict__ vlen,
            float* __restrict__ ws) {
  const float* rq    = ws + RQ_OFF;
  const float* kpart = ws + KPART_OFF;
  float* M = ws + M_OFF;
  const int id = blockIdx.x;            // 0..1023
  const int b = id >> 9;
  const int qb = (id & 511) * 4;
  const int t = threadIdx.x, w = t >> 6, l = t & 63;
  const int q = qb + w;
  const int vl = vlen[b];
  float m = -3e38f;
  for (int k0 = l * 4; k0 < vl; k0 += 256) {
    const float4 v = *(const float4*)(bias + (size_t)q * KK_ + k0);
    m = fmaxf(m, (k0 + 0 < vl) ? v.x : -3e38f);
    m = fmaxf(m, (k0 + 1 < vl) ? v.y : -3e38f);
    m = fmaxf(m, (k0 + 2 < vl) ? v.z : -3e38f);
    m = fmaxf(m, (k0 + 3 < vl) ? v.w : -3e38f);
  }
#pragma unroll
  for (int off = 1; off < 64; off <<= 1) m = fmaxf(m, __shfl_xor(m, off));
  if (l < 16) {
    const int h = l;
    float kmx = 0.f;
#pragma unroll
    for (int cc = 0; cc < 8; ++cc) kmx = fmaxf(kmx, kpart[(b * HH + h) * 8 + cc]);
    M[(size_t)(b * HH + h) * QQ + q] = rq[(size_t)(b * HH + h) * QQ + q] * kmx + m;
  }
}

// ---------------------------------------------------------------------------
// Main fused kernel. wg = (b,h, 64 q-rows), 256 thr (4 waves, 16 q each).
// Transposed-S MFMA: S^T = K*Q^T; lane (fr,g) holds P^T[k=c*16+g*4+r][q].
// That register layout IS the B-fragment of mfma_f32_16x16x16f16, so PV runs
// ctx^T = V^T * P^T with P never touching LDS (no Pt buffer, no drain).
// Kl and Vt are double-buffered -> ONE barrier per tile in each pass.
// Fixed per-row upper bound M (prep kernels) removes per-tile reductions.
// ---------------------------------------------------------------------------
__global__ __launch_bounds__(256, 4)
void fused_attn(const float* __restrict__ qs, const float* __restrict__ ks,
                const float* __restrict__ vs, const float* __restrict__ bias,
                const int* __restrict__ vlen, const float* __restrict__ ws,
                float* __restrict__ dout) {
  float* ctx  = dout;
  float* attn = dout + CTX_ELEMS;
  const float* Mbuf = ws + M_OFF;

  // XCD swizzle: XCD x owns q-tiles {4x..4x+3} x all 32 bh (bias L2-resident)
  const int x   = blockIdx.x;           // 0..1023
  const int xcd = x & 7;
  const int idx = x >> 3;               // 0..127, bh fastest
  const int qt  = xcd * 4 + (idx >> 5); // 0..31
  const int bh  = idx & 31;
  const int h   = bh & 15, b = bh >> 4;
  const int vl  = vlen[b];
  const int ntv = (vl + 63) >> 6;

  const int t = threadIdx.x;
  const int w = t >> 6, l = t & 63, fr = l & 15, g = l >> 4;
  const int q0 = qt * 64, qw = q0 + w * 16;
  const int myq = qw + fr;

  __shared__ _Float16 Kl[2][64][72];  // K tile [k][d], double-buffered
  __shared__ _Float16 Vt[2][64][72];  // V^T tile [dv][k], double-buffered

  // ---- zero-fill fully-masked attn tail ----
  {
    const int row = t >> 2;
    const int c0  = (t & 3) << 4;
    float* ap = attn + ((size_t)(b * HH + h) * QQ + q0 + row) * KK_ + c0;
    const f32x4 z = {0.f, 0.f, 0.f, 0.f};
    for (int k0 = ntv * 64; k0 < KK_; k0 += 64) {
      *(f32x4*)(ap + k0)      = z;
      *(f32x4*)(ap + k0 + 4)  = z;
      *(f32x4*)(ap + k0 + 8)  = z;
      *(f32x4*)(ap + k0 + 12) = z;
    }
  }

  // ---- Q B-fragments in registers, pre-scaled by 1/8 ----
  f16x8 bq[2];
  {
    const float* qp = qs + ((size_t)(b * QQ + myq) * HH + h) * DD + g * 8;
#pragma unroll
    for (int kk = 0; kk < 2; ++kk) {
      const float4 f0 = *(const float4*)(qp + kk * 32);
      const float4 f1 = *(const float4*)(qp + kk * 32 + 4);
      f16x8 v;
      v[0] = (_Float16)(f0.x * 0.125f); v[1] = (_Float16)(f0.y * 0.125f);
      v[2] = (_Float16)(f0.z * 0.125f); v[3] = (_Float16)(f0.w * 0.125f);
      v[4] = (_Float16)(f1.x * 0.125f); v[5] = (_Float16)(f1.y * 0.125f);
      v[6] = (_Float16)(f1.z * 0.125f); v[7] = (_Float16)(f1.w * 0.125f);
      bq[kk] = v;
    }
  }

  const float Mq = Mbuf[(size_t)(b * HH + h) * QQ + myq];
  const float* biasq = bias + (size_t)myq * KK_;
  float* attnq = attn + ((size_t)(b * HH + h) * QQ + myq) * KK_;

  const int krow = t >> 2, kc0 = (t & 3) << 4;   // K staging
  const int rho = t & 31, dlt = t >> 5;          // V staging (pairs)

#define KADDR(k) (ks + ((size_t)(b * KK_ + (k)) * HH + h) * DD)
#define VADDR(k) (vs + ((size_t)(b * KK_ + (k)) * HH + h) * DVV)

#define LOAD_K(k0arg)                                      \
  {                                                        \
    const float* kp = KADDR((k0arg) + krow) + kc0;         \
    _Pragma("unroll") for (int i = 0; i < 4; ++i)          \
      kr[i] = ((const float4*)kp)[i];                      \
  }

#define STORE_K(buf)                                       \
  {                                                        \
    _Pragma("unroll") for (int i = 0; i < 4; ++i) {        \
      f16x4 hv;                                            \
      hv[0] = (_Float16)kr[i].x; hv[1] = (_Float16)kr[i].y;\
      hv[2] = (_Float16)kr[i].z; hv[3] = (_Float16)kr[i].w;\
      *(f16x4*)&Kl[buf][krow][kc0 + i * 4] = hv;           \
    }                                                      \
  }

#define LOAD_V(k0arg)                                      \
  {                                                        \
    const float* vp0 = VADDR((k0arg) + 2 * rho) + dlt * 8; \
    vr[0] = ((const float4*)vp0)[0];                       \
    vr[1] = ((const float4*)vp0)[1];                       \
    const float* vp1 = VADDR((k0arg) + 2 * rho + 1) + dlt * 8; \
    vr[2] = ((const float4*)vp1)[0];                       \
    vr[3] = ((const float4*)vp1)[1];                       \
  }

#define STORE_V(buf)                                       \
  {                                                        \
    const float a0[8] = {vr[0].x, vr[0].y, vr[0].z, vr[0].w,\
                         vr[1].x, vr[1].y, vr[1].z, vr[1].w};\
    const float a1[8] = {vr[2].x, vr[2].y, vr[2].z, vr[2].w,\
                         vr[3].x, vr[3].y, vr[3].z, vr[3].w};\
    _Pragma("unroll") for (int i = 0; i < 8; ++i) {        \
      f16x2 pk; pk[0] = (_Float16)a0[i]; pk[1] = (_Float16)a1[i];\
      *(f16x2*)&Vt[buf][dlt * 8 + i][2 * rho] = pk;        \
    }                                                      \
  }

  float4 kr[4];
  float4 vr[4];
  int cur = 0;

  // ================= PASS 1: lsum with fixed M (1 barrier/tile) ==============
  LOAD_K(0);
  STORE_K(0);
  __syncthreads();

  float lsum = 0.f;
  for (int it = 0; it < ntv; ++it) {
    const int k0 = it * 64;
    const bool pre = (it + 1 < ntv);
    float4 bz[4];
#pragma unroll
    for (int c = 0; c < 4; ++c)
      bz[c] = *(const float4*)(biasq + k0 + c * 16 + g * 4);
    if (pre) LOAD_K(k0 + 64);
#pragma unroll
    for (int c = 0; c < 4; ++c) {
      f32x4 acc = {0.f, 0.f, 0.f, 0.f};
#pragma unroll
      for (int kk = 0; kk < 2; ++kk) {
        const f16x8 ka = *(const f16x8*)&Kl[cur][c * 16 + fr][kk * 32 + g * 8];
        acc = __builtin_amdgcn_mfma_f32_16x16x32_f16(ka, bq[kk], acc, 0, 0, 0);
      }
      const int kb = k0 + c * 16 + g * 4;
      const float e0 = __expf(acc[0] + bz[c].x - Mq);
      const float e1 = __expf(acc[1] + bz[c].y - Mq);
      const float e2 = __expf(acc[2] + bz[c].z - Mq);
      const float e3 = __expf(acc[3] + bz[c].w - Mq);
      lsum += (kb + 0 < vl) ? e0 : 0.f;
      lsum += (kb + 1 < vl) ? e1 : 0.f;
      lsum += (kb + 2 < vl) ? e2 : 0.f;
      lsum += (kb + 3 < vl) ? e3 : 0.f;
    }
    if (pre) STORE_K(cur ^ 1);   // other buffer: no race with readers of cur
    __syncthreads();             // ONE barrier per tile
    cur ^= 1;
  }
  lsum += __shfl_xor(lsum, 16);
  lsum += __shfl_xor(lsum, 32);
  const float il = 1.f / lsum;

  // ================= PASS 2: attn write + PV (1 barrier/tile) ================
  f32x4 accv[4];   // ctx^T: accv[dvblk]: C col=q(fr), row=dv(g*4+reg)
#pragma unroll
  for (int n = 0; n < 4; ++n) accv[n] = (f32x4){0.f, 0.f, 0.f, 0.f};

  cur = 0;
  LOAD_K(0);
  LOAD_V(0);
  STORE_K(0);
  STORE_V(0);
  __syncthreads();

  for (int it = 0; it < ntv; ++it) {
    const int k0 = it * 64;
    const bool pre = (it + 1 < ntv);
    float4 bz[4];
#pragma unroll
    for (int c = 0; c < 4; ++c)
      bz[c] = *(const float4*)(biasq + k0 + c * 16 + g * 4);
    if (pre) {
      LOAD_K(k0 + 64);
      LOAD_V(k0 + 64);
    }
#pragma unroll
    for (int c = 0; c < 4; ++c) {
      f32x4 acc = {0.f, 0.f, 0.f, 0.f};
#pragma unroll
      for (int kk = 0; kk < 2; ++kk) {
        const f16x8 ka = *(const f16x8*)&Kl[cur][c * 16 + fr][kk * 32 + g * 8];
        acc = __builtin_amdgcn_mfma_f32_16x16x32_f16(ka, bq[kk], acc, 0, 0, 0);
      }
      const int kb = k0 + c * 16 + g * 4;
      const float e0 = __expf(acc[0] + bz[c].x - Mq) * il;
      const float e1 = __expf(acc[1] + bz[c].y - Mq) * il;
      const float e2 = __expf(acc[2] + bz[c].z - Mq) * il;
      const float e3 = __expf(acc[3] + bz[c].w - Mq) * il;
      f32x4 pv;
      pv[0] = (kb + 0 < vl) ? e0 : 0.f;
      pv[1] = (kb + 1 < vl) ? e1 : 0.f;
      pv[2] = (kb + 2 < vl) ? e2 : 0.f;
      pv[3] = (kb + 3 < vl) ? e3 : 0.f;
      *(f32x4*)(attnq + kb) = pv;      // regular store: L2 merges lines
      // P^T fragment (B-operand of 16x16x16): lane (fr,g) holds k=g*4+e, n=fr
      f16x4 ph;
      ph[0] = (_Float16)pv[0]; ph[1] = (_Float16)pv[1];
      ph[2] = (_Float16)pv[2]; ph[3] = (_Float16)pv[3];
      // PV: ctx^T[dv][q] += V^T[dv][k] * P^T[k][q], k-block = c
#pragma unroll
      for (int n = 0; n < 4; ++n) {
        const f16x4 va = *(const f16x4*)&Vt[cur][n * 16 + fr][c * 16 + g * 4];
        accv[n] = __builtin_amdgcn_mfma_f32_16x16x16f16(va, ph, accv[n], 0, 0, 0);
      }
    }
    if (pre) {
      STORE_K(cur ^ 1);
      STORE_V(cur ^ 1);
    }
    __syncthreads();             // ONE barrier per tile
    cur ^= 1;
  }

  // ---- ctx store: q = qw+fr, dv = n*16 + g*4 + r (4 contiguous -> float4) ----
#pragma unroll
  for (int n = 0; n < 4; ++n) {
    const size_t o = ((size_t)(b * QQ + qw + fr) * HH + h) * DVV + n * 16 + g * 4;
    *(f32x4*)(ctx + o) = accv[n];
  }
#undef KADDR
#undef VADDR
#undef LOAD_K
#undef STORE_K
#undef LOAD_V
#undef STORE_V
}

// ---------------------------------------------------------------------------
extern "C" void kernel_launch(void* const* d_in, const int* in_sizes, int n_in,
                              void* d_out, int out_size, void* d_ws, size_t ws_size,
                              hipStream_t stream) {
  (void)in_sizes; (void)n_in; (void)ws_size; (void)out_size;
  const float* qs   = (const float*)d_in[0];
  const float* ks   = (const float*)d_in[1];
  const float* vs   = (const float*)d_in[2];
  const float* bias = (const float*)d_in[3];
  const int*   vlen = (const int*)d_in[4];
  float* out = (float*)d_out;
  float* ws  = (float*)d_ws;

  prep_norms<<<dim3(256), dim3(256), 0, stream>>>(qs, ks, vlen, ws);
  prep_m<<<dim3(1024), dim3(256), 0, stream>>>(bias, vlen, ws);
  fused_attn<<<dim3(1024), dim3(256), 0, stream>>>(qs, ks, vs, bias, vlen, ws, out);
}

// Round 8
// 266.013 us; speedup vs baseline: 1.7581x; 1.0906x over previous
//
#include <hip/hip_runtime.h>
#include <cstdint>
#include <cstddef>

#define BB 2
#define QQ 2048
#define KK_ 2048
#define HH 16
#define DD 64
#define DVV 64
#define NEG_INF_F (-1e9f)

static constexpr size_t CTX_ELEMS = (size_t)BB * QQ * HH * DVV;  // 4,194,304

typedef _Float16 f16x8 __attribute__((ext_vector_type(8)));
typedef _Float16 f16x4 __attribute__((ext_vector_type(4)));
typedef _Float16 f16x2 __attribute__((ext_vector_type(2)));
typedef float    f32x4 __attribute__((ext_vector_type(4)));

// workspace layout (float offsets)
#define RQ_OFF    0        // [B][H][Q]  0.125*||q_row||
#define KPART_OFF 65536    // [B*H][8]   partial max ||k_row|| per chunk
#define M_OFF     65792    // [B][H][Q]  upper bound M per row

// ---------------------------------------------------------------------------
// Prep A: per (b,h,chunk): rq rows + partial kmax (over valid k only).
// ---------------------------------------------------------------------------
__global__ __launch_bounds__(256)
void prep_norms(const float* __restrict__ qs, const float* __restrict__ ks,
                const int* __restrict__ vlen, float* __restrict__ ws) {
  float* rq    = ws + RQ_OFF;
  float* kpart = ws + KPART_OFF;
  const int id = blockIdx.x;            // 0..255
  const int bh = id & 31, c = id >> 5;  // chunk 0..7
  const int h = bh & 15, b = bh >> 4;
  const int vl = vlen[b];
  const int t = threadIdx.x;
  const int grp = t >> 4, l16 = t & 15;
  const int w = t >> 6, l = t & 63;
  __shared__ float red[4];
  float km2 = 0.f;                      // max squared norm
  const int base = c * 256;
  for (int i = 0; i < 16; ++i) {
    const int r = base + i * 16 + grp;
    {
      const float4 v = *(const float4*)(qs + ((size_t)(b * QQ + r) * HH + h) * DD + l16 * 4);
      float s = v.x * v.x + v.y * v.y + v.z * v.z + v.w * v.w;
      s += __shfl_xor(s, 1); s += __shfl_xor(s, 2);
      s += __shfl_xor(s, 4); s += __shfl_xor(s, 8);
      if (l16 == 0) rq[(size_t)(b * HH + h) * QQ + r] = sqrtf(s) * 0.125f;
    }
    if (r < vl) {
      const float4 v = *(const float4*)(ks + ((size_t)(b * KK_ + r) * HH + h) * DD + l16 * 4);
      float s = v.x * v.x + v.y * v.y + v.z * v.z + v.w * v.w;
      s += __shfl_xor(s, 1); s += __shfl_xor(s, 2);
      s += __shfl_xor(s, 4); s += __shfl_xor(s, 8);
      km2 = fmaxf(km2, s);
    }
  }
  km2 = fmaxf(km2, __shfl_xor(km2, 16));
  km2 = fmaxf(km2, __shfl_xor(km2, 32));
  if (l == 0) red[w] = km2;
  __syncthreads();
  if (t == 0)
    kpart[bh * 8 + c] = sqrtf(fmaxf(fmaxf(red[0], red[1]), fmaxf(red[2], red[3])));
}

// ---------------------------------------------------------------------------
// Prep B: per (b,q): Brow = max_{k<vl} bias[q,k]; M[b,h,q] = rq*kmax + Brow.
// ---------------------------------------------------------------------------
__global__ __launch_bounds__(256)
void prep_m(const float* __restrict__ bias, const int* __restrict__ vlen,
            float* __restrict__ ws) {
  const float* rq    = ws + RQ_OFF;
  const float* kpart = ws + KPART_OFF;
  float* M = ws + M_OFF;
  const int id = blockIdx.x;            // 0..1023
  const int b = id >> 9;
  const int qb = (id & 511) * 4;
  const int t = threadIdx.x, w = t >> 6, l = t & 63;
  const int q = qb + w;
  const int vl = vlen[b];
  float m = -3e38f;
  for (int k0 = l * 4; k0 < vl; k0 += 256) {
    const float4 v = *(const float4*)(bias + (size_t)q * KK_ + k0);
    m = fmaxf(m, (k0 + 0 < vl) ? v.x : -3e38f);
    m = fmaxf(m, (k0 + 1 < vl) ? v.y : -3e38f);
    m = fmaxf(m, (k0 + 2 < vl) ? v.z : -3e38f);
    m = fmaxf(m, (k0 + 3 < vl) ? v.w : -3e38f);
  }
#pragma unroll
  for (int off = 1; off < 64; off <<= 1) m = fmaxf(m, __shfl_xor(m, off));
  if (l < 16) {
    const int h = l;
    float kmx = 0.f;
#pragma unroll
    for (int cc = 0; cc < 8; ++cc) kmx = fmaxf(kmx, kpart[(b * HH + h) * 8 + cc]);
    M[(size_t)(b * HH + h) * QQ + q] = rq[(size_t)(b * HH + h) * QQ + q] * kmx + m;
  }
}

// ---------------------------------------------------------------------------
// Main fused kernel. wg = (b,h, 128 q-rows), 256 thr (4 waves).
// Each wave owns TWO 16-row q-fragments (32 q-rows) -> K/V LDS reads and
// global K/V fetches are shared across both fragments (half traffic/q-row).
// Transposed-S MFMA: S^T = K*Q^T; lane (fr,g) holds P^T[k][q] which IS the
// B-fragment of mfma_f32_16x16x16f16 -> PV from registers (no P LDS).
// Kl/Vt double-buffered -> ONE barrier per tile. Fixed per-row bound M.
// ---------------------------------------------------------------------------
__global__ __launch_bounds__(256, 2)
void fused_attn(const float* __restrict__ qs, const float* __restrict__ ks,
                const float* __restrict__ vs, const float* __restrict__ bias,
                const int* __restrict__ vlen, const float* __restrict__ ws,
                float* __restrict__ dout) {
  float* ctx  = dout;
  float* attn = dout + CTX_ELEMS;
  const float* Mbuf = ws + M_OFF;

  // XCD swizzle: XCD x owns q-tiles {2x,2x+1} x all 32 bh (bias 2MB/XCD in L2)
  const int x   = blockIdx.x;           // 0..511
  const int xcd = x & 7;
  const int j   = x >> 3;               // 0..63
  const int qt  = xcd * 2 + (j & 1);    // 0..15 (128-row tiles)
  const int bh  = j >> 1;               // 0..31
  const int h   = bh & 15, b = bh >> 4;
  const int vl  = vlen[b];
  const int ntv = (vl + 63) >> 6;

  const int t = threadIdx.x;
  const int w = t >> 6, l = t & 63, fr = l & 15, g = l >> 4;
  const int q0 = qt * 128, qw = q0 + w * 32;
  const int qA = qw + fr;               // fragment A q-row
  const int qB = qw + 16 + fr;          // fragment B q-row

  __shared__ _Float16 Kl[2][64][72];  // K tile [k][d], double-buffered
  __shared__ _Float16 Vt[2][64][72];  // V^T tile [dv][k], double-buffered

  // ---- zero-fill fully-masked attn tail ----
  {
    const int row = t >> 1;             // 0..127
    const int c0  = (t & 1) << 5;       // 0 or 32
    float* ap = attn + ((size_t)(b * HH + h) * QQ + q0 + row) * KK_ + c0;
    const f32x4 z = {0.f, 0.f, 0.f, 0.f};
    for (int k0 = ntv * 64; k0 < KK_; k0 += 64) {
#pragma unroll
      for (int i = 0; i < 8; ++i) *(f32x4*)(ap + k0 + i * 4) = z;
    }
  }

  // ---- Q B-fragments in registers, pre-scaled by 1/8 ----
  f16x8 bqA[2], bqB[2];
#define LOAD_Q(dst, qrow)                                               \
  {                                                                     \
    const float* qp = qs + ((size_t)(b * QQ + (qrow)) * HH + h) * DD + g * 8; \
    _Pragma("unroll") for (int kk = 0; kk < 2; ++kk) {                  \
      const float4 f0 = *(const float4*)(qp + kk * 32);                 \
      const float4 f1 = *(const float4*)(qp + kk * 32 + 4);             \
      f16x8 v;                                                          \
      v[0] = (_Float16)(f0.x * 0.125f); v[1] = (_Float16)(f0.y * 0.125f); \
      v[2] = (_Float16)(f0.z * 0.125f); v[3] = (_Float16)(f0.w * 0.125f); \
      v[4] = (_Float16)(f1.x * 0.125f); v[5] = (_Float16)(f1.y * 0.125f); \
      v[6] = (_Float16)(f1.z * 0.125f); v[7] = (_Float16)(f1.w * 0.125f); \
      dst[kk] = v;                                                      \
    }                                                                   \
  }
  LOAD_Q(bqA, qA);
  LOAD_Q(bqB, qB);
#undef LOAD_Q

  const float MqA = Mbuf[(size_t)(b * HH + h) * QQ + qA];
  const float MqB = Mbuf[(size_t)(b * HH + h) * QQ + qB];
  const float* biasA = bias + (size_t)qA * KK_;
  const float* biasB = bias + (size_t)qB * KK_;
  float* attnA = attn + ((size_t)(b * HH + h) * QQ + qA) * KK_;
  float* attnB = attn + ((size_t)(b * HH + h) * QQ + qB) * KK_;

  const int krow = t >> 2, kc0 = (t & 3) << 4;   // K staging
  const int rho = t & 31, dlt = t >> 5;          // V staging (pairs)

#define KADDR(k) (ks + ((size_t)(b * KK_ + (k)) * HH + h) * DD)
#define VADDR(k) (vs + ((size_t)(b * KK_ + (k)) * HH + h) * DVV)

#define LOAD_K(k0arg)                                      \
  {                                                        \
    const float* kp = KADDR((k0arg) + krow) + kc0;         \
    _Pragma("unroll") for (int i = 0; i < 4; ++i)          \
      kr[i] = ((const float4*)kp)[i];                      \
  }

#define STORE_K(buf)                                       \
  {                                                        \
    _Pragma("unroll") for (int i = 0; i < 4; ++i) {        \
      f16x4 hv;                                            \
      hv[0] = (_Float16)kr[i].x; hv[1] = (_Float16)kr[i].y;\
      hv[2] = (_Float16)kr[i].z; hv[3] = (_Float16)kr[i].w;\
      *(f16x4*)&Kl[buf][krow][kc0 + i * 4] = hv;           \
    }                                                      \
  }

#define LOAD_V(k0arg)                                      \
  {                                                        \
    const float* vp0 = VADDR((k0arg) + 2 * rho) + dlt * 8; \
    vr[0] = ((const float4*)vp0)[0];                       \
    vr[1] = ((const float4*)vp0)[1];                       \
    const float* vp1 = VADDR((k0arg) + 2 * rho + 1) + dlt * 8; \
    vr[2] = ((const float4*)vp1)[0];                       \
    vr[3] = ((const float4*)vp1)[1];                       \
  }

#define STORE_V(buf)                                       \
  {                                                        \
    const float a0[8] = {vr[0].x, vr[0].y, vr[0].z, vr[0].w,\
                         vr[1].x, vr[1].y, vr[1].z, vr[1].w};\
    const float a1[8] = {vr[2].x, vr[2].y, vr[2].z, vr[2].w,\
                         vr[3].x, vr[3].y, vr[3].z, vr[3].w};\
    _Pragma("unroll") for (int i = 0; i < 8; ++i) {        \
      f16x2 pk; pk[0] = (_Float16)a0[i]; pk[1] = (_Float16)a1[i];\
      *(f16x2*)&Vt[buf][dlt * 8 + i][2 * rho] = pk;        \
    }                                                      \
  }

  float4 kr[4];
  float4 vr[4];
  int cur = 0;

  // ================= PASS 1: lsum with fixed M (1 barrier/tile) ==============
  LOAD_K(0);
  STORE_K(0);
  __syncthreads();

  float lsumA = 0.f, lsumB = 0.f;
  for (int it = 0; it < ntv; ++it) {
    const int k0 = it * 64;
    const bool pre = (it + 1 < ntv);
    if (pre) LOAD_K(k0 + 64);
#pragma unroll
    for (int c = 0; c < 4; ++c) {
      const int kb = k0 + c * 16 + g * 4;
      const float4 bzA = *(const float4*)(biasA + kb);
      const float4 bzB = *(const float4*)(biasB + kb);
      f16x8 ka0 = *(const f16x8*)&Kl[cur][c * 16 + fr][g * 8];
      f16x8 ka1 = *(const f16x8*)&Kl[cur][c * 16 + fr][32 + g * 8];
      f32x4 aA = {0.f, 0.f, 0.f, 0.f};
      aA = __builtin_amdgcn_mfma_f32_16x16x32_f16(ka0, bqA[0], aA, 0, 0, 0);
      aA = __builtin_amdgcn_mfma_f32_16x16x32_f16(ka1, bqA[1], aA, 0, 0, 0);
      f32x4 aB = {0.f, 0.f, 0.f, 0.f};
      aB = __builtin_amdgcn_mfma_f32_16x16x32_f16(ka0, bqB[0], aB, 0, 0, 0);
      aB = __builtin_amdgcn_mfma_f32_16x16x32_f16(ka1, bqB[1], aB, 0, 0, 0);
#pragma unroll
      for (int r = 0; r < 4; ++r) {
        const float eA = __expf(aA[r] + bzA[r == 0 ? 0 : r] - MqA);
        const float eB = __expf(aB[r] + bzB[r] - MqB);
        lsumA += (kb + r < vl) ? eA : 0.f;
        lsumB += (kb + r < vl) ? eB : 0.f;
      }
    }
    if (pre) STORE_K(cur ^ 1);
    __syncthreads();             // ONE barrier per tile
    cur ^= 1;
  }
  lsumA += __shfl_xor(lsumA, 16); lsumA += __shfl_xor(lsumA, 32);
  lsumB += __shfl_xor(lsumB, 16); lsumB += __shfl_xor(lsumB, 32);
  const float ilA = 1.f / lsumA;
  const float ilB = 1.f / lsumB;

  // ================= PASS 2: attn write + PV (1 barrier/tile) ================
  f32x4 accvA[4], accvB[4];   // ctx^T: col=q(fr), row=dv(g*4+reg)
#pragma unroll
  for (int n = 0; n < 4; ++n) {
    accvA[n] = (f32x4){0.f, 0.f, 0.f, 0.f};
    accvB[n] = (f32x4){0.f, 0.f, 0.f, 0.f};
  }

  cur = 0;
  LOAD_K(0);
  LOAD_V(0);
  STORE_K(0);
  STORE_V(0);
  __syncthreads();

  for (int it = 0; it < ntv; ++it) {
    const int k0 = it * 64;
    const bool pre = (it + 1 < ntv);
    if (pre) {
      LOAD_K(k0 + 64);
      LOAD_V(k0 + 64);
    }
#pragma unroll
    for (int c = 0; c < 4; ++c) {
      const int kb = k0 + c * 16 + g * 4;
      const float4 bzA = *(const float4*)(biasA + kb);
      const float4 bzB = *(const float4*)(biasB + kb);
      f16x8 ka0 = *(const f16x8*)&Kl[cur][c * 16 + fr][g * 8];
      f16x8 ka1 = *(const f16x8*)&Kl[cur][c * 16 + fr][32 + g * 8];
      f32x4 aA = {0.f, 0.f, 0.f, 0.f};
      aA = __builtin_amdgcn_mfma_f32_16x16x32_f16(ka0, bqA[0], aA, 0, 0, 0);
      aA = __builtin_amdgcn_mfma_f32_16x16x32_f16(ka1, bqA[1], aA, 0, 0, 0);
      f32x4 aB = {0.f, 0.f, 0.f, 0.f};
      aB = __builtin_amdgcn_mfma_f32_16x16x32_f16(ka0, bqB[0], aB, 0, 0, 0);
      aB = __builtin_amdgcn_mfma_f32_16x16x32_f16(ka1, bqB[1], aB, 0, 0, 0);
      f32x4 pvA, pvB;
#pragma unroll
      for (int r = 0; r < 4; ++r) {
        const float eA = __expf(aA[r] + bzA[r] - MqA) * ilA;
        const float eB = __expf(aB[r] + bzB[r] - MqB) * ilB;
        pvA[r] = (kb + r < vl) ? eA : 0.f;
        pvB[r] = (kb + r < vl) ? eB : 0.f;
      }
      *(f32x4*)(attnA + kb) = pvA;     // regular stores: L2 merges lines
      *(f32x4*)(attnB + kb) = pvB;
      f16x4 phA, phB;
#pragma unroll
      for (int r = 0; r < 4; ++r) { phA[r] = (_Float16)pvA[r]; phB[r] = (_Float16)pvB[r]; }
      // PV: ctx^T[dv][q] += V^T[dv][k] * P^T[k][q]; va shared by both frags
#pragma unroll
      for (int n = 0; n < 4; ++n) {
        const f16x4 va = *(const f16x4*)&Vt[cur][n * 16 + fr][c * 16 + g * 4];
        accvA[n] = __builtin_amdgcn_mfma_f32_16x16x16f16(va, phA, accvA[n], 0, 0, 0);
        accvB[n] = __builtin_amdgcn_mfma_f32_16x16x16f16(va, phB, accvB[n], 0, 0, 0);
      }
    }
    if (pre) {
      STORE_K(cur ^ 1);
      STORE_V(cur ^ 1);
    }
    __syncthreads();             // ONE barrier per tile
    cur ^= 1;
  }

  // ---- ctx store: q = qA/qB, dv = n*16 + g*4 (+r contiguous -> float4) ----
#pragma unroll
  for (int n = 0; n < 4; ++n) {
    const size_t oA = ((size_t)(b * QQ + qA) * HH + h) * DVV + n * 16 + g * 4;
    const size_t oB = ((size_t)(b * QQ + qB) * HH + h) * DVV + n * 16 + g * 4;
    *(f32x4*)(ctx + oA) = accvA[n];
    *(f32x4*)(ctx + oB) = accvB[n];
  }
#undef KADDR
#undef VADDR
#undef LOAD_K
#undef STORE_K
#undef LOAD_V
#undef STORE_V
}

// ---------------------------------------------------------------------------
extern "C" void kernel_launch(void* const* d_in, const int* in_sizes, int n_in,
                              void* d_out, int out_size, void* d_ws, size_t ws_size,
                              hipStream_t stream) {
  (void)in_sizes; (void)n_in; (void)ws_size; (void)out_size;
  const float* qs   = (const float*)d_in[0];
  const float* ks   = (const float*)d_in[1];
  const float* vs   = (const float*)d_in[2];
  const float* bias = (const float*)d_in[3];
  const int*   vlen = (const int*)d_in[4];
  float* out = (float*)d_out;
  float* ws  = (float*)d_ws;

  prep_norms<<<dim3(256), dim3(256), 0, stream>>>(qs, ks, vlen, ws);
  prep_m<<<dim3(1024), dim3(256), 0, stream>>>(bias, vlen, ws);
  fused_attn<<<dim3(512), dim3(256), 0, stream>>>(qs, ks, vs, bias, vlen, ws, out);
}

// Round 9
// 252.561 us; speedup vs baseline: 1.8517x; 1.0533x over previous
//
#include <hip/hip_runtime.h>
#include <cstdint>
#include <cstddef>

#define BB 2
#define QQ 2048
#define KK_ 2048
#define HH 16
#define DD 64
#define DVV 64
#define NEG_INF_F (-1e9f)

static constexpr size_t CTX_ELEMS = (size_t)BB * QQ * HH * DVV;  // 4,194,304

typedef _Float16 f16x8 __attribute__((ext_vector_type(8)));
typedef _Float16 f16x4 __attribute__((ext_vector_type(4)));
typedef _Float16 f16x2 __attribute__((ext_vector_type(2)));
typedef float    f32x4 __attribute__((ext_vector_type(4)));

// workspace layout (float offsets)
#define RQ_OFF    0        // [B][H][Q]  0.125*||q_row||
#define KPART_OFF 65536    // [B*H][8]   partial max ||k_row|| per chunk
#define M_OFF     65792    // [B][H][Q]  upper bound M per row

// ---------------------------------------------------------------------------
// Prep A: per (b,h,chunk): rq rows + partial kmax (over valid k only).
// ---------------------------------------------------------------------------
__global__ __launch_bounds__(256)
void prep_norms(const float* __restrict__ qs, const float* __restrict__ ks,
                const int* __restrict__ vlen, float* __restrict__ ws) {
  float* rq    = ws + RQ_OFF;
  float* kpart = ws + KPART_OFF;
  const int id = blockIdx.x;            // 0..255
  const int bh = id & 31, c = id >> 5;  // chunk 0..7
  const int h = bh & 15, b = bh >> 4;
  const int vl = vlen[b];
  const int t = threadIdx.x;
  const int grp = t >> 4, l16 = t & 15;
  const int w = t >> 6, l = t & 63;
  __shared__ float red[4];
  float km2 = 0.f;                      // max squared norm
  const int base = c * 256;
  for (int i = 0; i < 16; ++i) {
    const int r = base + i * 16 + grp;
    {
      const float4 v = *(const float4*)(qs + ((size_t)(b * QQ + r) * HH + h) * DD + l16 * 4);
      float s = v.x * v.x + v.y * v.y + v.z * v.z + v.w * v.w;
      s += __shfl_xor(s, 1); s += __shfl_xor(s, 2);
      s += __shfl_xor(s, 4); s += __shfl_xor(s, 8);
      if (l16 == 0) rq[(size_t)(b * HH + h) * QQ + r] = sqrtf(s) * 0.125f;
    }
    if (r < vl) {
      const float4 v = *(const float4*)(ks + ((size_t)(b * KK_ + r) * HH + h) * DD + l16 * 4);
      float s = v.x * v.x + v.y * v.y + v.z * v.z + v.w * v.w;
      s += __shfl_xor(s, 1); s += __shfl_xor(s, 2);
      s += __shfl_xor(s, 4); s += __shfl_xor(s, 8);
      km2 = fmaxf(km2, s);
    }
  }
  km2 = fmaxf(km2, __shfl_xor(km2, 16));
  km2 = fmaxf(km2, __shfl_xor(km2, 32));
  if (l == 0) red[w] = km2;
  __syncthreads();
  if (t == 0)
    kpart[bh * 8 + c] = sqrtf(fmaxf(fmaxf(red[0], red[1]), fmaxf(red[2], red[3])));
}

// ---------------------------------------------------------------------------
// Prep B: per (b,q): Brow = max_{k<vl} bias[q,k]; M[b,h,q] = rq*kmax + Brow.
// ---------------------------------------------------------------------------
__global__ __launch_bounds__(256)
void prep_m(const float* __restrict__ bias, const int* __restrict__ vlen,
            float* __restrict__ ws) {
  const float* rq    = ws + RQ_OFF;
  const float* kpart = ws + KPART_OFF;
  float* M = ws + M_OFF;
  const int id = blockIdx.x;            // 0..1023
  const int b = id >> 9;
  const int qb = (id & 511) * 4;
  const int t = threadIdx.x, w = t >> 6, l = t & 63;
  const int q = qb + w;
  const int vl = vlen[b];
  float m = -3e38f;
  for (int k0 = l * 4; k0 < vl; k0 += 256) {
    const float4 v = *(const float4*)(bias + (size_t)q * KK_ + k0);
    m = fmaxf(m, (k0 + 0 < vl) ? v.x : -3e38f);
    m = fmaxf(m, (k0 + 1 < vl) ? v.y : -3e38f);
    m = fmaxf(m, (k0 + 2 < vl) ? v.z : -3e38f);
    m = fmaxf(m, (k0 + 3 < vl) ? v.w : -3e38f);
  }
#pragma unroll
  for (int off = 1; off < 64; off <<= 1) m = fmaxf(m, __shfl_xor(m, off));
  if (l < 16) {
    const int h = l;
    float kmx = 0.f;
#pragma unroll
    for (int cc = 0; cc < 8; ++cc) kmx = fmaxf(kmx, kpart[(b * HH + h) * 8 + cc]);
    M[(size_t)(b * HH + h) * QQ + q] = rq[(size_t)(b * HH + h) * QQ + q] * kmx + m;
  }
}

// ---------------------------------------------------------------------------
// Main fused kernel. wg = (b,h, 128 q-rows), 512 thr (8 waves, 16 q each).
// Grid 512 -> 2 blocks/CU x 8 waves = 16 waves/CU (round-7 TLP) while keeping
// round-8's per-CU K/V/bias fetch (2 q-tile streams per CU).
// Transposed-S MFMA: S^T = K*Q^T; lane (fr,g) holds P^T[k][q] which IS the
// B-fragment of mfma_f32_16x16x16f16 -> PV from registers (no P LDS).
// Kl/Vt double-buffered -> ONE barrier per tile. Fixed per-row bound M.
// ---------------------------------------------------------------------------
__global__ __launch_bounds__(512, 4)
void fused_attn(const float* __restrict__ qs, const float* __restrict__ ks,
                const float* __restrict__ vs, const float* __restrict__ bias,
                const int* __restrict__ vlen, const float* __restrict__ ws,
                float* __restrict__ dout) {
  float* ctx  = dout;
  float* attn = dout + CTX_ELEMS;
  const float* Mbuf = ws + M_OFF;

  // XCD swizzle: XCD x owns q-tiles {2x,2x+1} x all 32 bh (bias 2MB/XCD in L2)
  // q-tile-fastest ordering also interleaves b=0/b=1 blocks -> CU load balance.
  const int x   = blockIdx.x;           // 0..511
  const int xcd = x & 7;
  const int j   = x >> 3;               // 0..63
  const int qt  = xcd * 2 + (j & 1);    // 0..15 (128-row tiles)
  const int bh  = j >> 1;               // 0..31
  const int h   = bh & 15, b = bh >> 4;
  const int vl  = vlen[b];
  const int ntv = (vl + 63) >> 6;

  const int t = threadIdx.x;
  const int w = t >> 6, l = t & 63, fr = l & 15, g = l >> 4;
  const int q0 = qt * 128, qw = q0 + w * 16;
  const int myq = qw + fr;

  __shared__ _Float16 Kl[2][64][72];  // K tile [k][d], double-buffered
  __shared__ _Float16 Vt[2][64][72];  // V^T tile [dv][k], double-buffered

  // ---- zero-fill fully-masked attn tail ----
  {
    const int row = t >> 2;             // 0..127
    const int c0  = (t & 3) << 4;
    float* ap = attn + ((size_t)(b * HH + h) * QQ + q0 + row) * KK_ + c0;
    const f32x4 z = {0.f, 0.f, 0.f, 0.f};
    for (int k0 = ntv * 64; k0 < KK_; k0 += 64) {
#pragma unroll
      for (int i = 0; i < 4; ++i) *(f32x4*)(ap + k0 + i * 4) = z;
    }
  }

  // ---- Q B-fragment in registers, pre-scaled by 1/8 ----
  f16x8 bq[2];
  {
    const float* qp = qs + ((size_t)(b * QQ + myq) * HH + h) * DD + g * 8;
#pragma unroll
    for (int kk = 0; kk < 2; ++kk) {
      const float4 f0 = *(const float4*)(qp + kk * 32);
      const float4 f1 = *(const float4*)(qp + kk * 32 + 4);
      f16x8 v;
      v[0] = (_Float16)(f0.x * 0.125f); v[1] = (_Float16)(f0.y * 0.125f);
      v[2] = (_Float16)(f0.z * 0.125f); v[3] = (_Float16)(f0.w * 0.125f);
      v[4] = (_Float16)(f1.x * 0.125f); v[5] = (_Float16)(f1.y * 0.125f);
      v[6] = (_Float16)(f1.z * 0.125f); v[7] = (_Float16)(f1.w * 0.125f);
      bq[kk] = v;
    }
  }

  const float Mq = Mbuf[(size_t)(b * HH + h) * QQ + myq];
  const float* biasq = bias + (size_t)myq * KK_;
  float* attnq = attn + ((size_t)(b * HH + h) * QQ + myq) * KK_;

  // staging (512 threads): K 64x64 -> 8 floats/thread; V pairs -> 4 dv x 2 k
  const int krow = t >> 3, kc0 = (t & 7) << 3;
  const int rho = t & 31, dlt = t >> 5;          // dlt 0..15

#define KADDR(k) (ks + ((size_t)(b * KK_ + (k)) * HH + h) * DD)
#define VADDR(k) (vs + ((size_t)(b * KK_ + (k)) * HH + h) * DVV)

#define LOAD_K(k0arg)                                      \
  {                                                        \
    const float* kp = KADDR((k0arg) + krow) + kc0;         \
    kr[0] = ((const float4*)kp)[0];                        \
    kr[1] = ((const float4*)kp)[1];                        \
  }

#define STORE_K(buf)                                       \
  {                                                        \
    _Pragma("unroll") for (int i = 0; i < 2; ++i) {        \
      f16x4 hv;                                            \
      hv[0] = (_Float16)kr[i].x; hv[1] = (_Float16)kr[i].y;\
      hv[2] = (_Float16)kr[i].z; hv[3] = (_Float16)kr[i].w;\
      *(f16x4*)&Kl[buf][krow][kc0 + i * 4] = hv;           \
    }                                                      \
  }

#define LOAD_V(k0arg)                                      \
  {                                                        \
    vr[0] = *(const float4*)(VADDR((k0arg) + 2 * rho) + dlt * 4);     \
    vr[1] = *(const float4*)(VADDR((k0arg) + 2 * rho + 1) + dlt * 4); \
  }

#define STORE_V(buf)                                       \
  {                                                        \
    const float a0[4] = {vr[0].x, vr[0].y, vr[0].z, vr[0].w}; \
    const float a1[4] = {vr[1].x, vr[1].y, vr[1].z, vr[1].w}; \
    _Pragma("unroll") for (int i = 0; i < 4; ++i) {        \
      f16x2 pk; pk[0] = (_Float16)a0[i]; pk[1] = (_Float16)a1[i];\
      *(f16x2*)&Vt[buf][dlt * 4 + i][2 * rho] = pk;        \
    }                                                      \
  }

  float4 kr[2];
  float4 vr[2];
  int cur = 0;

  // ================= PASS 1: lsum with fixed M (1 barrier/tile) ==============
  LOAD_K(0);
  STORE_K(0);
  __syncthreads();

  float lsum = 0.f;
  for (int it = 0; it < ntv; ++it) {
    const int k0 = it * 64;
    const bool pre = (it + 1 < ntv);
    if (pre) LOAD_K(k0 + 64);
#pragma unroll
    for (int c = 0; c < 4; ++c) {
      const int kb = k0 + c * 16 + g * 4;
      const float4 bz = *(const float4*)(biasq + kb);
      const f16x8 ka0 = *(const f16x8*)&Kl[cur][c * 16 + fr][g * 8];
      const f16x8 ka1 = *(const f16x8*)&Kl[cur][c * 16 + fr][32 + g * 8];
      f32x4 acc = {0.f, 0.f, 0.f, 0.f};
      acc = __builtin_amdgcn_mfma_f32_16x16x32_f16(ka0, bq[0], acc, 0, 0, 0);
      acc = __builtin_amdgcn_mfma_f32_16x16x32_f16(ka1, bq[1], acc, 0, 0, 0);
#pragma unroll
      for (int r = 0; r < 4; ++r) {
        const float e = __expf(acc[r] + bz[r] - Mq);
        lsum += (kb + r < vl) ? e : 0.f;
      }
    }
    if (pre) STORE_K(cur ^ 1);
    __syncthreads();             // ONE barrier per tile
    cur ^= 1;
  }
  lsum += __shfl_xor(lsum, 16);
  lsum += __shfl_xor(lsum, 32);
  const float il = 1.f / lsum;

  // ================= PASS 2: attn write + PV (1 barrier/tile) ================
  f32x4 accv[4];   // ctx^T: col=q(fr), row=dv(g*4+reg)
#pragma unroll
  for (int n = 0; n < 4; ++n) accv[n] = (f32x4){0.f, 0.f, 0.f, 0.f};

  cur = 0;
  LOAD_K(0);
  LOAD_V(0);
  STORE_K(0);
  STORE_V(0);
  __syncthreads();

  for (int it = 0; it < ntv; ++it) {
    const int k0 = it * 64;
    const bool pre = (it + 1 < ntv);
    if (pre) {
      LOAD_K(k0 + 64);
      LOAD_V(k0 + 64);
    }
#pragma unroll
    for (int c = 0; c < 4; ++c) {
      const int kb = k0 + c * 16 + g * 4;
      const float4 bz = *(const float4*)(biasq + kb);
      const f16x8 ka0 = *(const f16x8*)&Kl[cur][c * 16 + fr][g * 8];
      const f16x8 ka1 = *(const f16x8*)&Kl[cur][c * 16 + fr][32 + g * 8];
      f32x4 acc = {0.f, 0.f, 0.f, 0.f};
      acc = __builtin_amdgcn_mfma_f32_16x16x32_f16(ka0, bq[0], acc, 0, 0, 0);
      acc = __builtin_amdgcn_mfma_f32_16x16x32_f16(ka1, bq[1], acc, 0, 0, 0);
      f32x4 pv;
#pragma unroll
      for (int r = 0; r < 4; ++r) {
        const float e = __expf(acc[r] + bz[r] - Mq) * il;
        pv[r] = (kb + r < vl) ? e : 0.f;
      }
      *(f32x4*)(attnq + kb) = pv;      // regular store: L2 merges lines
      // P^T fragment (B-operand of 16x16x16): lane (fr,g) holds k=g*4+e, n=fr
      f16x4 ph;
#pragma unroll
      for (int r = 0; r < 4; ++r) ph[r] = (_Float16)pv[r];
      // PV: ctx^T[dv][q] += V^T[dv][k] * P^T[k][q], k-block = c
#pragma unroll
      for (int n = 0; n < 4; ++n) {
        const f16x4 va = *(const f16x4*)&Vt[cur][n * 16 + fr][c * 16 + g * 4];
        accv[n] = __builtin_amdgcn_mfma_f32_16x16x16f16(va, ph, accv[n], 0, 0, 0);
      }
    }
    if (pre) {
      STORE_K(cur ^ 1);
      STORE_V(cur ^ 1);
    }
    __syncthreads();             // ONE barrier per tile
    cur ^= 1;
  }

  // ---- ctx store: q = myq, dv = n*16 + g*4 (+r contiguous -> float4) ----
#pragma unroll
  for (int n = 0; n < 4; ++n) {
    const size_t o = ((size_t)(b * QQ + myq) * HH + h) * DVV + n * 16 + g * 4;
    *(f32x4*)(ctx + o) = accv[n];
  }
#undef KADDR
#undef VADDR
#undef LOAD_K
#undef STORE_K
#undef LOAD_V
#undef STORE_V
}

// ---------------------------------------------------------------------------
extern "C" void kernel_launch(void* const* d_in, const int* in_sizes, int n_in,
                              void* d_out, int out_size, void* d_ws, size_t ws_size,
                              hipStream_t stream) {
  (void)in_sizes; (void)n_in; (void)ws_size; (void)out_size;
  const float* qs   = (const float*)d_in[0];
  const float* ks   = (const float*)d_in[1];
  const float* vs   = (const float*)d_in[2];
  const float* bias = (const float*)d_in[3];
  const int*   vlen = (const int*)d_in[4];
  float* out = (float*)d_out;
  float* ws  = (float*)d_ws;

  prep_norms<<<dim3(256), dim3(256), 0, stream>>>(qs, ks, vlen, ws);
  prep_m<<<dim3(1024), dim3(256), 0, stream>>>(bias, vlen, ws);
  fused_attn<<<dim3(512), dim3(512), 0, stream>>>(qs, ks, vs, bias, vlen, ws, out);
}

// Round 10
// 250.668 us; speedup vs baseline: 1.8657x; 1.0075x over previous
//
#include <hip/hip_runtime.h>
#include <cstdint>
#include <cstddef>

#define BB 2
#define QQ 2048
#define KK_ 2048
#define HH 16
#define DD 64
#define DVV 64

static constexpr size_t CTX_ELEMS = (size_t)BB * QQ * HH * DVV;  // 4,194,304
#define LOG2E 1.44269504088896f
#define QSCALE (LOG2E / 8.0f)

typedef _Float16 f16x8 __attribute__((ext_vector_type(8)));
typedef _Float16 f16x4 __attribute__((ext_vector_type(4)));
typedef _Float16 f16x2 __attribute__((ext_vector_type(2)));
typedef float    f32x4 __attribute__((ext_vector_type(4)));

__device__ __forceinline__ float fexp2(float x) {
  float r;
  asm("v_exp_f32 %0, %1" : "=v"(r) : "v"(x));
  return r;
}

// workspace layout (float offsets)
#define RQ_OFF    0        // [B][H][Q]  0.125*||q_row||
#define KPART_OFF 65536    // [B*H][8]   partial max ||k_row|| per chunk
#define M_OFF     65792    // [B][H][Q]  upper bound M per row

// ---------------------------------------------------------------------------
// Prep A: per (b,h,chunk): rq rows + partial kmax (over valid k only).
// ---------------------------------------------------------------------------
__global__ __launch_bounds__(256)
void prep_norms(const float* __restrict__ qs, const float* __restrict__ ks,
                const int* __restrict__ vlen, float* __restrict__ ws) {
  float* rq    = ws + RQ_OFF;
  float* kpart = ws + KPART_OFF;
  const int id = blockIdx.x;            // 0..255
  const int bh = id & 31, c = id >> 5;  // chunk 0..7
  const int h = bh & 15, b = bh >> 4;
  const int vl = vlen[b];
  const int t = threadIdx.x;
  const int grp = t >> 4, l16 = t & 15;
  const int w = t >> 6, l = t & 63;
  __shared__ float red[4];
  float km2 = 0.f;                      // max squared norm
  const int base = c * 256;
  for (int i = 0; i < 16; ++i) {
    const int r = base + i * 16 + grp;
    {
      const float4 v = *(const float4*)(qs + ((size_t)(b * QQ + r) * HH + h) * DD + l16 * 4);
      float s = v.x * v.x + v.y * v.y + v.z * v.z + v.w * v.w;
      s += __shfl_xor(s, 1); s += __shfl_xor(s, 2);
      s += __shfl_xor(s, 4); s += __shfl_xor(s, 8);
      if (l16 == 0) rq[(size_t)(b * HH + h) * QQ + r] = sqrtf(s) * 0.125f;
    }
    if (r < vl) {
      const float4 v = *(const float4*)(ks + ((size_t)(b * KK_ + r) * HH + h) * DD + l16 * 4);
      float s = v.x * v.x + v.y * v.y + v.z * v.z + v.w * v.w;
      s += __shfl_xor(s, 1); s += __shfl_xor(s, 2);
      s += __shfl_xor(s, 4); s += __shfl_xor(s, 8);
      km2 = fmaxf(km2, s);
    }
  }
  km2 = fmaxf(km2, __shfl_xor(km2, 16));
  km2 = fmaxf(km2, __shfl_xor(km2, 32));
  if (l == 0) red[w] = km2;
  __syncthreads();
  if (t == 0)
    kpart[bh * 8 + c] = sqrtf(fmaxf(fmaxf(red[0], red[1]), fmaxf(red[2], red[3])));
}

// ---------------------------------------------------------------------------
// Prep B: per (b,q): Brow = max_{k<vl} bias[q,k]; M[b,h,q] = rq*kmax + Brow.
// ---------------------------------------------------------------------------
__global__ __launch_bounds__(256)
void prep_m(const float* __restrict__ bias, const int* __restrict__ vlen,
            float* __restrict__ ws) {
  const float* rq    = ws + RQ_OFF;
  const float* kpart = ws + KPART_OFF;
  float* M = ws + M_OFF;
  const int id = blockIdx.x;            // 0..1023
  const int b = id >> 9;
  const int qb = (id & 511) * 4;
  const int t = threadIdx.x, w = t >> 6, l = t & 63;
  const int q = qb + w;
  const int vl = vlen[b];
  float m = -3e38f;
  for (int k0 = l * 4; k0 < vl; k0 += 256) {
    const float4 v = *(const float4*)(bias + (size_t)q * KK_ + k0);
    m = fmaxf(m, (k0 + 0 < vl) ? v.x : -3e38f);
    m = fmaxf(m, (k0 + 1 < vl) ? v.y : -3e38f);
    m = fmaxf(m, (k0 + 2 < vl) ? v.z : -3e38f);
    m = fmaxf(m, (k0 + 3 < vl) ? v.w : -3e38f);
  }
#pragma unroll
  for (int off = 1; off < 64; off <<= 1) m = fmaxf(m, __shfl_xor(m, off));
  if (l < 16) {
    const int h = l;
    float kmx = 0.f;
#pragma unroll
    for (int cc = 0; cc < 8; ++cc) kmx = fmaxf(kmx, kpart[(b * HH + h) * 8 + cc]);
    M[(size_t)(b * HH + h) * QQ + q] = rq[(size_t)(b * HH + h) * QQ + q] * kmx + m;
  }
}

// ---------------------------------------------------------------------------
// Main fused kernel. wg = (b,h, 128 q-rows), 512 thr (8 waves, 16 q each).
// K-step 128: two 64-row sub-buffers per pair, double-buffered pairs ->
// ONE barrier per 128 k-cols. 8 independent c-blocks per barrier period give
// the scheduler room to hide bias/L2 latency.
// exp2 folding: Q pre-scaled by log2e/8; MFMA C initialized to -M*log2e
// (pass1) or log2(il)-M*log2e (pass2) -> per element just fma + v_exp_f32.
// Transposed-S MFMA: lane (fr,g) holds P^T[k][q] = B-frag of 16x16x16f16
// -> PV from registers. Mask applied only in the last pair (uniform branch).
// ---------------------------------------------------------------------------
__global__ __launch_bounds__(512, 4)
void fused_attn(const float* __restrict__ qs, const float* __restrict__ ks,
                const float* __restrict__ vs, const float* __restrict__ bias,
                const int* __restrict__ vlen, const float* __restrict__ ws,
                float* __restrict__ dout) {
  float* ctx  = dout;
  float* attn = dout + CTX_ELEMS;
  const float* Mbuf = ws + M_OFF;

  // XCD swizzle: XCD x owns q-tiles {2x,2x+1} x all 32 bh (bias 2MB/XCD in L2)
  const int x   = blockIdx.x;           // 0..511
  const int xcd = x & 7;
  const int j   = x >> 3;               // 0..63
  const int qt  = xcd * 2 + (j & 1);    // 0..15 (128-row tiles)
  const int bh  = j >> 1;               // 0..31
  const int h   = bh & 15, b = bh >> 4;
  const int vl  = vlen[b];
  const int ntv = (vl + 63) >> 6;       // valid 64-tiles
  const int np  = (ntv + 1) >> 1;       // 128-wide pairs (may pad 1 tile)

  const int t = threadIdx.x;
  const int w = t >> 6, l = t & 63, fr = l & 15, g = l >> 4;
  const int q0 = qt * 128, qw = q0 + w * 16;
  const int myq = qw + fr;

  __shared__ _Float16 KS[4][64][72];  // K: two pairs x two 64-row halves
  __shared__ _Float16 VS[4][64][72];  // V^T: same structure

  // ---- zero-fill attn tail beyond processed range ----
  {
    const int row = t >> 2;             // 0..127
    const int c0  = (t & 3) << 4;
    float* ap = attn + ((size_t)(b * HH + h) * QQ + q0 + row) * KK_ + c0;
    const f32x4 z = {0.f, 0.f, 0.f, 0.f};
    for (int k0 = np * 128; k0 < KK_; k0 += 64) {
#pragma unroll
      for (int i = 0; i < 4; ++i) *(f32x4*)(ap + k0 + i * 4) = z;
    }
  }

  // ---- Q B-fragment in registers, pre-scaled by log2e/8 ----
  f16x8 bq[2];
  {
    const float* qp = qs + ((size_t)(b * QQ + myq) * HH + h) * DD + g * 8;
#pragma unroll
    for (int kk = 0; kk < 2; ++kk) {
      const float4 f0 = *(const float4*)(qp + kk * 32);
      const float4 f1 = *(const float4*)(qp + kk * 32 + 4);
      f16x8 v;
      v[0] = (_Float16)(f0.x * QSCALE); v[1] = (_Float16)(f0.y * QSCALE);
      v[2] = (_Float16)(f0.z * QSCALE); v[3] = (_Float16)(f0.w * QSCALE);
      v[4] = (_Float16)(f1.x * QSCALE); v[5] = (_Float16)(f1.y * QSCALE);
      v[6] = (_Float16)(f1.z * QSCALE); v[7] = (_Float16)(f1.w * QSCALE);
      bq[kk] = v;
    }
  }

  const float Mq2 = Mbuf[(size_t)(b * HH + h) * QQ + myq] * LOG2E;
  const float* biasq = bias + (size_t)myq * KK_;
  float* attnq = attn + ((size_t)(b * HH + h) * QQ + myq) * KK_;

  // staging: K 128x64 -> row t>>2, 16 cols (t&3)*16; V pairs per half
  const int krow = t >> 2, kc0 = (t & 3) << 4;
  const int h64 = t >> 8;               // V half 0/1
  const int tt = t & 255;
  const int rho = tt & 31, dlt = tt >> 5;  // dlt 0..7

#define KADDR(k) (ks + ((size_t)(b * KK_ + (k)) * HH + h) * DD)
#define VADDR(k) (vs + ((size_t)(b * KK_ + (k)) * HH + h) * DVV)

#define LOAD_K2(k0arg)                                     \
  {                                                        \
    const float* kp = KADDR((k0arg) + krow) + kc0;         \
    _Pragma("unroll") for (int i = 0; i < 4; ++i)          \
      kr[i] = ((const float4*)kp)[i];                      \
  }

#define STORE_K2(pb2)                                      \
  {                                                        \
    const int khalf = (pb2) + (krow >> 6);                 \
    const int krw = krow & 63;                             \
    _Pragma("unroll") for (int i = 0; i < 4; ++i) {        \
      f16x4 hv;                                            \
      hv[0] = (_Float16)kr[i].x; hv[1] = (_Float16)kr[i].y;\
      hv[2] = (_Float16)kr[i].z; hv[3] = (_Float16)kr[i].w;\
      *(f16x4*)&KS[khalf][krw][kc0 + i * 4] = hv;          \
    }                                                      \
  }

#define LOAD_V2(k0arg)                                     \
  {                                                        \
    const float* vp0 = VADDR((k0arg) + h64 * 64 + 2 * rho) + dlt * 8; \
    vr[0] = ((const float4*)vp0)[0];                       \
    vr[1] = ((const float4*)vp0)[1];                       \
    const float* vp1 = VADDR((k0arg) + h64 * 64 + 2 * rho + 1) + dlt * 8; \
    vr[2] = ((const float4*)vp1)[0];                       \
    vr[3] = ((const float4*)vp1)[1];                       \
  }

#define STORE_V2(pb2)                                      \
  {                                                        \
    const float a0[8] = {vr[0].x, vr[0].y, vr[0].z, vr[0].w,\
                         vr[1].x, vr[1].y, vr[1].z, vr[1].w};\
    const float a1[8] = {vr[2].x, vr[2].y, vr[2].z, vr[2].w,\
                         vr[3].x, vr[3].y, vr[3].z, vr[3].w};\
    _Pragma("unroll") for (int i = 0; i < 8; ++i) {        \
      f16x2 pk; pk[0] = (_Float16)a0[i]; pk[1] = (_Float16)a1[i];\
      *(f16x2*)&VS[(pb2) + h64][dlt * 8 + i][2 * rho] = pk;\
    }                                                      \
  }

  float4 kr[4];
  float4 vr[4];

  // ================= PASS 1: lsum (1 barrier per 128 k) ======================
  LOAD_K2(0);
  STORE_K2(0);
  __syncthreads();

  float lsum = 0.f;
  for (int ip = 0; ip < np; ++ip) {
    const int pb2 = (ip & 1) << 1;
    const bool pre = (ip + 1 < np);
    const bool mpair = (ip == np - 1);
    if (pre) LOAD_K2((ip + 1) * 128);
#pragma unroll
    for (int hf = 0; hf < 2; ++hf) {
#pragma unroll
      for (int c = 0; c < 4; ++c) {
        const int kb = ip * 128 + hf * 64 + c * 16 + g * 4;
        const float4 bz = *(const float4*)(biasq + kb);
        const f16x8 ka0 = *(const f16x8*)&KS[pb2 + hf][c * 16 + fr][g * 8];
        const f16x8 ka1 = *(const f16x8*)&KS[pb2 + hf][c * 16 + fr][32 + g * 8];
        f32x4 acc = {-Mq2, -Mq2, -Mq2, -Mq2};
        acc = __builtin_amdgcn_mfma_f32_16x16x32_f16(ka0, bq[0], acc, 0, 0, 0);
        acc = __builtin_amdgcn_mfma_f32_16x16x32_f16(ka1, bq[1], acc, 0, 0, 0);
        float e[4];
#pragma unroll
        for (int r = 0; r < 4; ++r) e[r] = fexp2(fmaf(bz[r], LOG2E, acc[r]));
        if (mpair) {
#pragma unroll
          for (int r = 0; r < 4; ++r) e[r] = (kb + r < vl) ? e[r] : 0.f;
        }
        lsum += (e[0] + e[1]) + (e[2] + e[3]);
      }
    }
    if (pre) STORE_K2(pb2 ^ 2);
    __syncthreads();             // ONE barrier per 128 k
  }
  lsum += __shfl_xor(lsum, 16);
  lsum += __shfl_xor(lsum, 32);
  const float ci = -__log2f(lsum) - Mq2;   // pass-2 C-init: log2(il) - M*log2e

  // ================= PASS 2: attn write + PV (1 barrier per 128 k) ===========
  f32x4 accv[4];   // ctx^T: col=q(fr), row=dv(g*4+reg)
#pragma unroll
  for (int n = 0; n < 4; ++n) accv[n] = (f32x4){0.f, 0.f, 0.f, 0.f};

  LOAD_K2(0);
  LOAD_V2(0);
  STORE_K2(0);
  STORE_V2(0);
  __syncthreads();

  for (int ip = 0; ip < np; ++ip) {
    const int pb2 = (ip & 1) << 1;
    const bool pre = (ip + 1 < np);
    const bool mpair = (ip == np - 1);
    if (pre) {
      LOAD_K2((ip + 1) * 128);
      LOAD_V2((ip + 1) * 128);
    }
#pragma unroll
    for (int hf = 0; hf < 2; ++hf) {
#pragma unroll
      for (int c = 0; c < 4; ++c) {
        const int kb = ip * 128 + hf * 64 + c * 16 + g * 4;
        const float4 bz = *(const float4*)(biasq + kb);
        const f16x8 ka0 = *(const f16x8*)&KS[pb2 + hf][c * 16 + fr][g * 8];
        const f16x8 ka1 = *(const f16x8*)&KS[pb2 + hf][c * 16 + fr][32 + g * 8];
        f32x4 acc = {ci, ci, ci, ci};
        acc = __builtin_amdgcn_mfma_f32_16x16x32_f16(ka0, bq[0], acc, 0, 0, 0);
        acc = __builtin_amdgcn_mfma_f32_16x16x32_f16(ka1, bq[1], acc, 0, 0, 0);
        f32x4 pv;
#pragma unroll
        for (int r = 0; r < 4; ++r) pv[r] = fexp2(fmaf(bz[r], LOG2E, acc[r]));
        if (mpair) {
#pragma unroll
          for (int r = 0; r < 4; ++r) pv[r] = (kb + r < vl) ? pv[r] : 0.f;
        }
        *(f32x4*)(attnq + kb) = pv;    // regular store: L2 merges lines
        // P^T fragment = B-operand of 16x16x16f16 (k=g*4+e, n=fr)
        f16x4 ph;
#pragma unroll
        for (int r = 0; r < 4; ++r) ph[r] = (_Float16)pv[r];
#pragma unroll
        for (int n = 0; n < 4; ++n) {
          const f16x4 va = *(const f16x4*)&VS[pb2 + hf][n * 16 + fr][c * 16 + g * 4];
          accv[n] = __builtin_amdgcn_mfma_f32_16x16x16f16(va, ph, accv[n], 0, 0, 0);
        }
      }
    }
    if (pre) {
      STORE_K2(pb2 ^ 2);
      STORE_V2(pb2 ^ 2);
    }
    __syncthreads();             // ONE barrier per 128 k
  }

  // ---- ctx store: q = myq, dv = n*16 + g*4 (+r contiguous -> float4) ----
#pragma unroll
  for (int n = 0; n < 4; ++n) {
    const size_t o = ((size_t)(b * QQ + myq) * HH + h) * DVV + n * 16 + g * 4;
    *(f32x4*)(ctx + o) = accv[n];
  }
#undef KADDR
#undef VADDR
#undef LOAD_K2
#undef STORE_K2
#undef LOAD_V2
#undef STORE_V2
}

// ---------------------------------------------------------------------------
extern "C" void kernel_launch(void* const* d_in, const int* in_sizes, int n_in,
                              void* d_out, int out_size, void* d_ws, size_t ws_size,
                              hipStream_t stream) {
  (void)in_sizes; (void)n_in; (void)ws_size; (void)out_size;
  const float* qs   = (const float*)d_in[0];
  const float* ks   = (const float*)d_in[1];
  const float* vs   = (const float*)d_in[2];
  const float* bias = (const float*)d_in[3];
  const int*   vlen = (const int*)d_in[4];
  float* out = (float*)d_out;
  float* ws  = (float*)d_ws;

  prep_norms<<<dim3(256), dim3(256), 0, stream>>>(qs, ks, vlen, ws);
  prep_m<<<dim3(1024), dim3(256), 0, stream>>>(bias, vlen, ws);
  fused_attn<<<dim3(512), dim3(512), 0, stream>>>(qs, ks, vs, bias, vlen, ws, out);
}